// Round 1
// baseline (573.782 us; speedup 1.0000x reference)
//
#include <hip/hip_runtime.h>

// PointLayerNorm: B=4, N=200000, C=96, S=32 segments (contiguous CSR in N).
// Semantics: per (b,s) layer-norm over all count[s]*C elements.
//   mean = sum(x)/(cnt*C); var = sum(x^2)/(cnt*C) - mean^2
//   out  = (x - mean) * rsqrt(var + 1e-5) * weight[c] + bias[c]

#define BB 4
#define NN 200000
#define CC 96
#define SS 32
#define CVV (CC / 4)                // 24 float4 per point
#define TOTALV (BB * NN * CVV)      // 19,200,000 float4 tasks (mult of 256)
#define NKEY (BB * SS)              // 128 (b,s) accumulators
#define CHUNK (37 * 256)            // 9472 float4s per block (mult of 256)

// ---------------------------------------------------------------- pass 1 ---
__global__ __launch_bounds__(256) void k_stats(
    const float4* __restrict__ x, const int* __restrict__ bidx,
    double* __restrict__ gsum, double* __restrict__ gsq) {
  __shared__ float lsum[NKEY];
  __shared__ float lsq[NKEY];
  const int tid = threadIdx.x;
  if (tid < NKEY) { lsum[tid] = 0.f; lsq[tid] = 0.f; }
  __syncthreads();

  const int start = blockIdx.x * CHUNK;
  const int end = min(start + CHUNK, TOTALV);  // end-start is a multiple of 256

  int key = -1;
  float as = 0.f, aq = 0.f;
  for (int f = start + tid; f < end; f += 256) {
    float4 v = x[f];
    unsigned p = (unsigned)f / (unsigned)CVV;   // b*N + n
    unsigned n = p % (unsigned)NN;
    unsigned b = p / (unsigned)NN;
    int k = (int)(b * SS) + bidx[n];
    float s = (v.x + v.y) + (v.z + v.w);
    float q = (v.x * v.x + v.y * v.y) + (v.z * v.z + v.w * v.w);
    if (k != key) {                 // rare: segment boundary inside block
      if (key >= 0) { atomicAdd(&lsum[key], as); atomicAdd(&lsq[key], aq); }
      key = k; as = 0.f; aq = 0.f;
    }
    as += s; aq += q;
  }

  // End flush: wave-uniform fast path (all 64 lanes same key almost always).
  if (key >= 0) {
    int fk = __builtin_amdgcn_readfirstlane(key);
    if (__all(key == fk)) {
      for (int off = 32; off; off >>= 1) {
        as += __shfl_xor(as, off, 64);
        aq += __shfl_xor(aq, off, 64);
      }
      if ((tid & 63) == 0) { atomicAdd(&lsum[key], as); atomicAdd(&lsq[key], aq); }
    } else {
      atomicAdd(&lsum[key], as); atomicAdd(&lsq[key], aq);
    }
  }
  __syncthreads();

  if (tid < NKEY) {
    float s = lsum[tid], q = lsq[tid];
    if (s != 0.f || q != 0.f) {
      atomicAdd(&gsum[tid], (double)s);
      atomicAdd(&gsq[tid], (double)q);
    }
  }
}

// ---------------------------------------------------------------- pass 2 ---
__global__ void k_finalize(const int* __restrict__ offs,
                           const double* __restrict__ gsum,
                           const double* __restrict__ gsq,
                           float2* __restrict__ stats) {
  int i = threadIdx.x;
  if (i < NKEY) {
    int s = i & (SS - 1);
    int cnt = offs[s + 1] - offs[s];
    double M = (double)cnt * (double)CC;
    double mean = gsum[i] / M;
    double var = gsq[i] / M - mean * mean;
    if (var < 0.0) var = 0.0;
    double inv = 1.0 / sqrt(var + 1e-5);
    stats[i] = make_float2((float)mean, (float)inv);
  }
}

// ---------------------------------------------------------------- pass 3 ---
__global__ __launch_bounds__(256) void k_norm(
    const float4* __restrict__ x, const int* __restrict__ bidx,
    const float2* __restrict__ stats, const float4* __restrict__ w4,
    const float4* __restrict__ b4, float4* __restrict__ out) {
  const int gstride = gridDim.x * 256;
  for (int f = blockIdx.x * 256 + threadIdx.x; f < TOTALV; f += gstride) {
    float4 v = x[f];
    unsigned p = (unsigned)f / (unsigned)CVV;   // b*N + n
    unsigned cv = (unsigned)f - p * (unsigned)CVV;
    unsigned n = p % (unsigned)NN;
    unsigned b = p / (unsigned)NN;
    float2 st = stats[b * SS + bidx[n]];
    float4 w = w4[cv];
    float4 bi = b4[cv];
    float4 o;
    o.x = (v.x - st.x) * st.y * w.x + bi.x;
    o.y = (v.y - st.x) * st.y * w.y + bi.y;
    o.z = (v.z - st.x) * st.y * w.z + bi.z;
    o.w = (v.w - st.x) * st.y * w.w + bi.w;
    out[f] = o;
  }
}

// --------------------------------------------------------------- launch ----
extern "C" void kernel_launch(void* const* d_in, const int* in_sizes, int n_in,
                              void* d_out, int out_size, void* d_ws,
                              size_t ws_size, hipStream_t stream) {
  const float* x = (const float*)d_in[0];
  const int* offs = (const int*)d_in[1];   // [S+1]
  const int* bidx = (const int*)d_in[2];   // [N]
  const float* w = (const float*)d_in[3];  // [C]
  const float* b = (const float*)d_in[4];  // [C]
  float* out = (float*)d_out;

  double* gsum = (double*)d_ws;
  double* gsq = gsum + NKEY;
  float2* stats = (float2*)(gsq + NKEY);

  // ws is re-poisoned to 0xAA before every launch — zero the accumulators.
  hipMemsetAsync(d_ws, 0, 2 * NKEY * sizeof(double), stream);

  const int g1 = (TOTALV + CHUNK - 1) / CHUNK;  // 2028 blocks
  k_stats<<<g1, 256, 0, stream>>>((const float4*)x, bidx, gsum, gsq);
  k_finalize<<<1, 128, 0, stream>>>(offs, gsum, gsq, stats);
  k_norm<<<2048, 256, 0, stream>>>((const float4*)x, bidx, stats,
                                   (const float4*)w, (const float4*)b,
                                   (float4*)out);
}